// Round 11
// baseline (189.598 us; speedup 1.0000x reference)
//
#include <hip/hip_runtime.h>

// N=50000, E=800000 (per relation), D=128, O=128, fp32 in/out.
// out = relu( spmm(adj1, X@W1) + spmm(adj2, X@W2) )
//      = relu( spmm(adj1, X) @ W1 + spmm(adj2, X) @ W2 )   [associativity]
//
// Pipeline (all on `stream`, graph-capture safe):
//   convert: Xb = bf16(X); Wt = bf16(W^T); block 0 zeroes gcur (no memset).
//   bin:     edges -> 782 64-row buckets (r7-proven LDS write-combining).
//   sort2:   per bucket: counting-sort edge list IN PLACE by seg =
//            (rowLocal,rel) [128 segs]; emit seg_ptr[129] per bucket.
//   agg:     block = (bucket, colgroup). cg -> XCD-pair via blockIdx&7:
//            each XCD gathers only its 32-col slice of Xb = 3.2MB < 4MB L2
//            (Xb row = 4 cache lines; slice = line cg of every row).
//            No LDS, no barriers: 16-lane groups walk seg ranges of the
//            sorted list, gather one 64B line/edge, store 64B/(row,rel).
//   gemm:    out = relu( agg0 @ W1 + agg1 @ W2 ) via 16x16x32 bf16 MFMA.
//
// r10 lesson (measured): agg ~55-58us across half/quarter/octant chunking
// (occ 51-67%) -> occupancy is NOT the limiter; the 410MB gather vs 4MB/XCD
// L2 is. This round: L2-resident column slices + build seg lists ONCE.

typedef __attribute__((ext_vector_type(4))) float     f32x4;
typedef __attribute__((ext_vector_type(8))) short     bf16x8;

#define NB      782     // 64-row buckets: ceil(50000/64)
#define BSLOTS  10      // LDS staging slots per bucket in bin
#define BCAP    2560    // capacity per bucket (mean 2048, ~11 sigma slack)
#define SPITCH  132     // seg_ptr row pitch (129 used)

static __device__ __forceinline__ unsigned short f2bf(float f) {
    unsigned u = __float_as_uint(f);
    u += 0x7FFF + ((u >> 16) & 1);           // round-to-nearest-even
    return (unsigned short)(u >> 16);
}
static __device__ __forceinline__ float b2f(unsigned short s) {
    return __uint_as_float((unsigned)s << 16);
}

// ---------------------------------------------------------------------------
// Convert: Wt[rel][o][k] = bf16(W_rel[k][o]), Xb = bf16(X); block 0 also
// zeroes gcur (replaces the memset dispatch; completes before bin launches).
// ---------------------------------------------------------------------------
__global__ __launch_bounds__(256) void convert_kernel(
    const float* __restrict__ X,
    const float* __restrict__ W1, const float* __restrict__ W2,
    unsigned short* __restrict__ Xb, unsigned short* __restrict__ Wt,
    int* __restrict__ gcur, int n)
{
    if (blockIdx.x == 0)
        for (int i = threadIdx.x; i < NB; i += 256) gcur[i] = 0;

    const int stride = gridDim.x * blockDim.x;
    const int nW = 2 * 128 * 128;
    const int nX = n * 32;                   // float4 count
    const int total = nW + nX;
    for (int g = blockIdx.x * blockDim.x + threadIdx.x; g < total; g += stride) {
        if (g < nW) {
            const int rel = g >> 14;
            const int o   = (g >> 7) & 127;
            const int k   = g & 127;
            const float* W = rel ? W2 : W1;
            Wt[g] = f2bf(W[k * 128 + o]);
        } else {
            const int i = g - nW;
            const float4 v = ((const float4*)X)[i];
            ushort4 b;
            b.x = f2bf(v.x); b.y = f2bf(v.y); b.z = f2bf(v.z); b.w = f2bf(v.w);
            ((ushort4*)Xb)[i] = b;
        }
    }
}

// ---------------------------------------------------------------------------
// Bin (r7-proven): scatter edges into 64-row buckets, LDS write-combining.
// pack = {val:f32 << 32 | col:16 << 7 | rel:1 << 6 | rowLocal:6}.
// ---------------------------------------------------------------------------
__global__ __launch_bounds__(256) void bin_kernel(
    const int* __restrict__ rows1, const int* __restrict__ cols1, const float* __restrict__ vals1,
    const int* __restrict__ rows2, const int* __restrict__ cols2, const float* __restrict__ vals2,
    int* __restrict__ gcur, unsigned long long* __restrict__ edges_tmp,
    int E, int n)
{
    __shared__ unsigned long long stage[NB][BSLOTS];
    __shared__ int scnt[NB];

    for (int i = threadIdx.x; i < NB; i += 256) scnt[i] = 0;
    __syncthreads();

    const int stride = gridDim.x * 256;
    const int total  = 2 * E;
    for (int g = blockIdx.x * 256 + threadIdx.x; g < total; g += stride) {
        int r, col, rel; float v;
        if (g < E) { r = rows1[g]; col = cols1[g]; rel = 0; v = vals1[g]; }
        else       { int e = g - E; r = rows2[e]; col = cols2[e]; rel = 1; v = vals2[e]; }

        const int b = r >> 6;
        const unsigned lo = (unsigned)(r & 63) | ((unsigned)rel << 6) | ((unsigned)col << 7);
        const unsigned long long pack =
            (unsigned long long)lo | ((unsigned long long)__float_as_uint(v) << 32);

        const int pos = atomicAdd(&scnt[b], 1);
        if (pos < BSLOTS) {
            stage[b][pos] = pack;
        } else {                                  // overflow: direct write
            int gp = atomicAdd(&gcur[b], 1);
            if (gp < BCAP) edges_tmp[(size_t)b * BCAP + gp] = pack;
        }
    }
    __syncthreads();

    for (int b = threadIdx.x; b < NB; b += 256) {
        int k = scnt[b]; if (k > BSLOTS) k = BSLOTS;
        if (k > 0) {
            int base = atomicAdd(&gcur[b], k);
            for (int i = 0; i < k; ++i)
                if (base + i < BCAP)
                    edges_tmp[(size_t)b * BCAP + base + i] = stage[b][i];
        }
    }
}

// ---------------------------------------------------------------------------
// Sort2: per bucket, counting-sort edges IN PLACE by seg = rowLocal*2 + rel
// (128 segs); write seg_ptr[129]. Hist -> 2x64 shfl scan -> scatter to LDS
// -> coalesced write-back.
// ---------------------------------------------------------------------------
__global__ __launch_bounds__(256) void sort2_kernel(
    const int* __restrict__ gcur,
    unsigned long long* __restrict__ edges_tmp,
    int* __restrict__ seg_ptr)
{
    __shared__ unsigned long long sout[BCAP];
    __shared__ int hist[128];
    __shared__ int ptr[129];
    __shared__ int cur[128];

    const int b   = blockIdx.x;
    const int tid = threadIdx.x;
    int sz = gcur[b]; if (sz > BCAP) sz = BCAP;
    unsigned long long* ebase = edges_tmp + (size_t)b * BCAP;

    if (tid < 128) hist[tid] = 0;
    __syncthreads();

    // Phase A: histogram
    for (int e = tid; e < sz; e += 256) {
        const unsigned lo = (unsigned)ebase[e];
        atomicAdd(&hist[((lo & 63u) << 1) | ((lo >> 6) & 1)], 1);
    }
    __syncthreads();

    // Phase B: exclusive scan of 128 (two 64-wide shfl scans + combine)
    if (tid < 128) {
        int v = hist[tid], x = v;
        #pragma unroll
        for (int off = 1; off < 64; off <<= 1) {
            int t = __shfl_up(x, off, 64);
            if ((tid & 63) >= off) x += t;
        }
        ptr[tid + 1] = x;
    }
    if (tid == 0) ptr[0] = 0;
    __syncthreads();
    if (tid >= 64 && tid < 128) {
        const int t = ptr[64];                 // group-0 total (lockstep wave)
        ptr[tid + 1] += t;
    }
    __syncthreads();
    if (tid < 128) cur[tid] = ptr[tid];
    __syncthreads();

    // Phase C: scatter into LDS at sorted positions
    for (int e = tid; e < sz; e += 256) {
        const unsigned long long p = ebase[e];
        const unsigned lo = (unsigned)p;
        const int pos = atomicAdd(&cur[((lo & 63u) << 1) | ((lo >> 6) & 1)], 1);
        sout[pos] = p;
    }
    __syncthreads();

    // Phase D: coalesced write-back (in place) + seg_ptr
    for (int e = tid; e < sz; e += 256) ebase[e] = sout[e];
    if (tid <= 128) seg_ptr[b * SPITCH + tid] = ptr[tid];
}

// ---------------------------------------------------------------------------
// Agg: block = (bucket b, colgroup cg). cg = (blockIdx&7)>>1 pins each cg to
// one XCD pair -> per-XCD gather working set = 3.2MB 32-col slice (L2-fit).
// 16 groups x 16 lanes; group walks segs s, s+16, ...; per edge: broadcast
// 8B pack + one 64B line gather; fp32 accum; bf16 64B store per (row,rel).
// ---------------------------------------------------------------------------
__global__ __launch_bounds__(256) void agg_kernel(
    const unsigned long long* __restrict__ edges_tmp,
    const int* __restrict__ seg_ptr,
    const unsigned short* __restrict__ Xb,
    unsigned short* __restrict__ agg, int n)
{
    const int tid  = threadIdx.x;
    const int lane = tid & 15;
    const int grp  = tid >> 4;

    const int orig = blockIdx.x;               // 3128 = 8 * 391
    const int xcd  = orig & 7;
    const int cg   = xcd >> 1;                 // colgroup -> XCD pair
    const int b    = ((orig >> 3) << 1) | (xcd & 1);

    const unsigned long long* ebase = edges_tmp + (size_t)b * BCAP;
    const int* sptr = seg_ptr + b * SPITCH;
    const int colbase = cg * 32 + lane * 2;

    for (int s = grp; s < 128; s += 16) {
        const int row = b * 64 + (s >> 1);
        if (row >= n) continue;
        const int rel = s & 1;
        const int e0 = sptr[s], e1 = sptr[s + 1];

        float ax = 0.f, ay = 0.f;
        int e = e0;
        for (; e + 4 <= e1; e += 4) {
            const unsigned long long p0 = ebase[e + 0];
            const unsigned long long p1 = ebase[e + 1];
            const unsigned long long p2 = ebase[e + 2];
            const unsigned long long p3 = ebase[e + 3];
            const unsigned c0 = ((unsigned)p0 >> 7) & 0xFFFFu;
            const unsigned c1 = ((unsigned)p1 >> 7) & 0xFFFFu;
            const unsigned c2 = ((unsigned)p2 >> 7) & 0xFFFFu;
            const unsigned c3 = ((unsigned)p3 >> 7) & 0xFFFFu;
            const ushort2 x0 = *(const ushort2*)&Xb[(size_t)c0 * 128 + colbase];
            const ushort2 x1 = *(const ushort2*)&Xb[(size_t)c1 * 128 + colbase];
            const ushort2 x2 = *(const ushort2*)&Xb[(size_t)c2 * 128 + colbase];
            const ushort2 x3 = *(const ushort2*)&Xb[(size_t)c3 * 128 + colbase];
            const float v0 = __uint_as_float((unsigned)(p0 >> 32));
            const float v1 = __uint_as_float((unsigned)(p1 >> 32));
            const float v2 = __uint_as_float((unsigned)(p2 >> 32));
            const float v3 = __uint_as_float((unsigned)(p3 >> 32));
            ax = fmaf(v0, b2f(x0.x), ax);  ay = fmaf(v0, b2f(x0.y), ay);
            ax = fmaf(v1, b2f(x1.x), ax);  ay = fmaf(v1, b2f(x1.y), ay);
            ax = fmaf(v2, b2f(x2.x), ax);  ay = fmaf(v2, b2f(x2.y), ay);
            ax = fmaf(v3, b2f(x3.x), ax);  ay = fmaf(v3, b2f(x3.y), ay);
        }
        for (; e < e1; ++e) {
            const unsigned long long p = ebase[e];
            const unsigned c = ((unsigned)p >> 7) & 0xFFFFu;
            const ushort2 xv = *(const ushort2*)&Xb[(size_t)c * 128 + colbase];
            const float v = __uint_as_float((unsigned)(p >> 32));
            ax = fmaf(v, b2f(xv.x), ax);  ay = fmaf(v, b2f(xv.y), ay);
        }

        ushort2 o;
        o.x = f2bf(ax);  o.y = f2bf(ay);
        *(ushort2*)&agg[((size_t)rel * n + row) * 128 + colbase] = o;
    }
}

// ---------------------------------------------------------------------------
// GEMM epilogue: out = relu( agg0 @ W1 + agg1 @ W2 ), bf16 MFMA, fp32 out.
// 32-row tiles. A-frag: row = lane&15, k = (lane>>4)*8 + j. C/D: col=lane&15,
// row=(lane>>4)*4+reg  [m89-verified].
// ---------------------------------------------------------------------------
__global__ __launch_bounds__(256) void gemm_relu_kernel(
    const unsigned short* __restrict__ agg,
    const unsigned short* __restrict__ Wt,
    float* __restrict__ out, int n)
{
    const int lane = threadIdx.x & 63;
    const int w    = threadIdx.x >> 6;
    const int colbase = w * 32;
    const int l15 = lane & 15;
    const int lhi = lane >> 4;

    bf16x8 bfrag[2][2][4];                   // [rel][ct][ks]
    #pragma unroll
    for (int rel = 0; rel < 2; ++rel) {
        const unsigned short* Wr = Wt + rel * 16384;
        #pragma unroll
        for (int ct = 0; ct < 2; ++ct) {
            const int o = colbase + ct * 16 + l15;
            #pragma unroll
            for (int ks = 0; ks < 4; ++ks)
                bfrag[rel][ct][ks] = *(const bf16x8*)&Wr[o * 128 + ks * 32 + lhi * 8];
        }
    }

    const int row0 = blockIdx.x * 32;
    const f32x4 zero = {0.f, 0.f, 0.f, 0.f};

    #pragma unroll
    for (int rt = 0; rt < 2; ++rt) {
        const int r0 = row0 + rt * 16;
        int ra = r0 + l15; if (ra >= n) ra = n - 1;   // clamp OOB reads
        bf16x8 af0[4], af1[4];
        #pragma unroll
        for (int ks = 0; ks < 4; ++ks) {
            af0[ks] = *(const bf16x8*)&agg[(size_t)ra * 128 + ks * 32 + lhi * 8];
            af1[ks] = *(const bf16x8*)&agg[((size_t)n + ra) * 128 + ks * 32 + lhi * 8];
        }

        f32x4 acc[2];
        acc[0] = zero; acc[1] = zero;
        #pragma unroll
        for (int ks = 0; ks < 4; ++ks) {
            acc[0] = __builtin_amdgcn_mfma_f32_16x16x32_bf16(af0[ks], bfrag[0][0][ks], acc[0], 0, 0, 0);
            acc[1] = __builtin_amdgcn_mfma_f32_16x16x32_bf16(af0[ks], bfrag[0][1][ks], acc[1], 0, 0, 0);
            acc[0] = __builtin_amdgcn_mfma_f32_16x16x32_bf16(af1[ks], bfrag[1][0][ks], acc[0], 0, 0, 0);
            acc[1] = __builtin_amdgcn_mfma_f32_16x16x32_bf16(af1[ks], bfrag[1][1][ks], acc[1], 0, 0, 0);
        }

        #pragma unroll
        for (int ct = 0; ct < 2; ++ct) {
            const int col = colbase + ct * 16 + l15;
            #pragma unroll
            for (int j = 0; j < 4; ++j) {
                const int r = r0 + lhi * 4 + j;
                if (r < n) out[(size_t)r * 128 + col] = fmaxf(acc[ct][j], 0.f);
            }
        }
    }
}

extern "C" void kernel_launch(void* const* d_in, const int* in_sizes, int n_in,
                              void* d_out, int out_size, void* d_ws, size_t ws_size,
                              hipStream_t stream)
{
    const float* X  = (const float*)d_in[0];
    const int*   r1 = (const int*)  d_in[1];
    const int*   c1 = (const int*)  d_in[2];
    const float* v1 = (const float*)d_in[3];
    const int*   r2 = (const int*)  d_in[4];
    const int*   c2 = (const int*)  d_in[5];
    const float* v2 = (const float*)d_in[6];
    const float* W1 = (const float*)d_in[7];
    const float* W2 = (const float*)d_in[8];
    float*       out = (float*)d_out;

    const int n = in_sizes[0] / 128;   // 50000
    const int E = in_sizes[1];         // 800000

    // Workspace layout (~55 MB):
    //   agg       : 2*n*128 bf16   (25.6 MB)
    //   Xb        : n*128 bf16     (12.8 MB)
    //   Wt        : 2*128*128 bf16 (64 KB)
    //   edges_tmp : NB*BCAP u64    (16.0 MB), 256B-aligned
    //   seg_ptr   : NB*SPITCH ints (412 KB)
    //   gcur      : NB ints
    unsigned short* agg = (unsigned short*)d_ws;
    unsigned short* Xb  = agg + (size_t)2 * n * 128;
    unsigned short* Wt  = Xb + (size_t)n * 128;
    unsigned long long* edges_tmp =
        (unsigned long long*)(((uintptr_t)(Wt + 2 * 128 * 128) + 255) & ~(uintptr_t)255);
    int* seg_ptr = (int*)(edges_tmp + (size_t)NB * BCAP);
    int* gcur    = seg_ptr + NB * SPITCH;

    // 1) convert (also zeroes gcur in block 0)
    convert_kernel<<<2048, 256, 0, stream>>>(X, W1, W2, Xb, Wt, gcur, n);

    // 2) bin edges into 64-row buckets
    bin_kernel<<<512, 256, 0, stream>>>(r1, c1, v1, r2, c2, v2, gcur, edges_tmp, E, n);

    // 3) counting-sort each bucket by (rowLocal, rel), in place
    sort2_kernel<<<NB, 256, 0, stream>>>(gcur, edges_tmp, seg_ptr);

    // 4) aggregate: (bucket, colgroup) blocks, L2-resident column slices
    agg_kernel<<<NB * 4, 256, 0, stream>>>(edges_tmp, seg_ptr, Xb, agg, n);

    // 5) GEMM + ReLU epilogue
    gemm_relu_kernel<<<(n + 31) / 32, 256, 0, stream>>>(agg, Wt, out, n);
}

// Round 12
// 137.739 us; speedup vs baseline: 1.3765x; 1.3765x over previous
//
#include <hip/hip_runtime.h>

// N=50000, E=800000 (per relation), D=128, O=128, fp32 in/out.
// out = relu( spmm(adj1, X@W1) + spmm(adj2, X@W2) )
//      = relu( spmm(adj1, X) @ W1 + spmm(adj2, X) @ W2 )   [associativity]
//
// Pipeline (all on `stream`, graph-capture safe):
//   convbin: [blocks 0..511]  bin: edges -> 782 64-row buckets, LDS
//            write-combined packs {val:f32 | col:16 | rel:1 | rowLocal:6}.
//            [blocks 512..767] convert: Xb = bf16(X), Wt = bf16(W^T).
//   aggemm:  one block per 16-row quarter (grid 3128, m204 swizzle).
//            Phase 1 (r7-proven): scan bucket list, scatter into 32
//            fixed-stride LDS seg-lists, per-seg 32-lane register gather
//            sum(val * Xb[col]) -> bf16 tile in LDS (pitch 136 = 2-way-free).
//            Phase 2: 4 waves MFMA the 16x128 tile against L2-resident Wt
//            (2 rels accumulated), fused ReLU, direct fp32 out store.
//            Deletes: agg global store, agg re-read, separate gemm launch.
//
// r11 lesson (measured): XCD pinning via blockIdx&7 is NOT durable (FETCH
// 150->226MB); never build locality on workgroup->XCD assignment.
// r9 lesson: work-stealing kills locality. Static swizzled chunks only.

typedef __attribute__((ext_vector_type(4))) float     f32x4;
typedef __attribute__((ext_vector_type(8))) short     bf16x8;

#define NB      782     // 64-row buckets: ceil(50000/64)
#define BSLOTS  10      // LDS staging slots per bucket in bin
#define BCAP    2560    // capacity per bucket (mean 2048, ~11 sigma slack)
#define SCAP    64      // per (row,rel) seg capacity (mean 16; P(>64)~2e-18)
#define BING    512     // bin blocks
#define CONVG   256     // convert blocks
#define TPITCH  136     // LDS tile pitch in shorts (17*16B -> bank-friendly)

static __device__ __forceinline__ unsigned short f2bf(float f) {
    unsigned u = __float_as_uint(f);
    u += 0x7FFF + ((u >> 16) & 1);           // round-to-nearest-even
    return (unsigned short)(u >> 16);
}
static __device__ __forceinline__ float b2f(unsigned short s) {
    return __uint_as_float((unsigned)s << 16);
}

// ---------------------------------------------------------------------------
// Fused: bin (blocks < BING) + convert (blocks >= BING).
// ---------------------------------------------------------------------------
__global__ __launch_bounds__(256) void convbin_kernel(
    const float* __restrict__ X,
    const float* __restrict__ W1, const float* __restrict__ W2,
    const int* __restrict__ rows1, const int* __restrict__ cols1, const float* __restrict__ vals1,
    const int* __restrict__ rows2, const int* __restrict__ cols2, const float* __restrict__ vals2,
    unsigned short* __restrict__ Xb, unsigned short* __restrict__ Wt,
    int* __restrict__ gcur, unsigned long long* __restrict__ edges_tmp,
    int E, int n)
{
    if (blockIdx.x >= BING) {
        // ---- convert role ----
        const int stride = CONVG * 256;
        const int nW = 2 * 128 * 128;
        const int nX = n * 32;               // float4 count
        const int total = nW + nX;
        for (int g = (blockIdx.x - BING) * 256 + threadIdx.x; g < total; g += stride) {
            if (g < nW) {
                const int rel = g >> 14;
                const int o   = (g >> 7) & 127;
                const int k   = g & 127;
                const float* W = rel ? W2 : W1;
                Wt[g] = f2bf(W[k * 128 + o]);
            } else {
                const int i = g - nW;
                const float4 v = ((const float4*)X)[i];
                ushort4 b;
                b.x = f2bf(v.x); b.y = f2bf(v.y); b.z = f2bf(v.z); b.w = f2bf(v.w);
                ((ushort4*)Xb)[i] = b;
            }
        }
        return;
    }

    // ---- bin role (r7/r10-proven) ----
    __shared__ unsigned long long stage[NB][BSLOTS];
    __shared__ int scnt[NB];

    for (int i = threadIdx.x; i < NB; i += 256) scnt[i] = 0;
    __syncthreads();

    const int stride = BING * 256;
    const int total  = 2 * E;
    for (int g = blockIdx.x * 256 + threadIdx.x; g < total; g += stride) {
        int r, col, rel; float v;
        if (g < E) { r = rows1[g]; col = cols1[g]; rel = 0; v = vals1[g]; }
        else       { int e = g - E; r = rows2[e]; col = cols2[e]; rel = 1; v = vals2[e]; }

        const int b = r >> 6;
        const unsigned lo = (unsigned)(r & 63) | ((unsigned)rel << 6) | ((unsigned)col << 7);
        const unsigned long long pack =
            (unsigned long long)lo | ((unsigned long long)__float_as_uint(v) << 32);

        const int pos = atomicAdd(&scnt[b], 1);
        if (pos < BSLOTS) {
            stage[b][pos] = pack;
        } else {                                  // overflow: direct write
            int gp = atomicAdd(&gcur[b], 1);
            if (gp < BCAP) edges_tmp[(size_t)b * BCAP + gp] = pack;
        }
    }
    __syncthreads();

    for (int b = threadIdx.x; b < NB; b += 256) {
        int k = scnt[b]; if (k > BSLOTS) k = BSLOTS;
        if (k > 0) {
            int base = atomicAdd(&gcur[b], k);
            for (int i = 0; i < k; ++i)
                if (base + i < BCAP)
                    edges_tmp[(size_t)b * BCAP + base + i] = stage[b][i];
        }
    }
}

// ---------------------------------------------------------------------------
// Aggemm: block = 16-row quarter-bucket. Gather into LDS bf16 tile, then
// in-block MFMA epilogue (out = relu(tile0 @ W1 + tile1 @ W2)).
// A-frag: row = lane&15, k = (lane>>4)*8 + j. C/D: col=lane&15,
// row=(lane>>4)*4+reg  [m89-verified].
// ---------------------------------------------------------------------------
__global__ __launch_bounds__(256) void aggemm_kernel(
    const int* __restrict__ gcur,
    const unsigned long long* __restrict__ edges_tmp,
    const unsigned short* __restrict__ Xb,
    const unsigned short* __restrict__ Wt,
    float* __restrict__ out, int n)
{
    __shared__ unsigned long long lists[32 * SCAP];       // 16 KB
    __shared__ int cnt[32];
    __shared__ unsigned short tile[2 * 16 * TPITCH];      // 8.5 KB, pitch 136

    const int tid = threadIdx.x;
    const int NQ  = NB * 4;                  // 3128 = 8 * 391
    // m204 bijective XCD swizzle (r8=0): consecutive swz (same bucket's
    // quarters) dispatch adjacently -> bucket edge-list reads L2-friendly.
    const int xcd = blockIdx.x & 7, bi = blockIdx.x >> 3;
    const int swz = xcd * (NQ >> 3) + bi;

    const int b   = swz >> 2;
    const int q   = swz & 3;
    const int rowbase = swz * 16;
    if (rowbase >= n) return;

    // ---- load B fragments early (hides under gather) ----
    const int lane64 = tid & 63;
    const int w      = tid >> 6;
    const int colbase = w * 32;
    const int l15 = lane64 & 15;
    const int lhi = lane64 >> 4;

    bf16x8 bfrag[2][2][4];                   // [rel][ct][ks]
    #pragma unroll
    for (int rel = 0; rel < 2; ++rel) {
        const unsigned short* Wr = Wt + rel * 16384;
        #pragma unroll
        for (int ct = 0; ct < 2; ++ct) {
            const int o = colbase + ct * 16 + l15;
            #pragma unroll
            for (int ks = 0; ks < 4; ++ks)
                bfrag[rel][ct][ks] = *(const bf16x8*)&Wr[o * 128 + ks * 32 + lhi * 8];
        }
    }

    int sz = gcur[b]; if (sz > BCAP) sz = BCAP;
    const unsigned long long* ebase = edges_tmp + (size_t)b * BCAP;

    if (tid < 32) cnt[tid] = 0;
    __syncthreads();

    // ---- Phase 1a: filter quarter, append to per-seg LDS lists ----
    for (int e = tid; e < sz; e += 256) {
        const unsigned long long p = ebase[e];
        const unsigned lo = (unsigned)p;
        const int rl = (int)(lo & 63u);
        if ((rl >> 4) == q) {
            const int seg = ((rl & 15) << 1) | ((lo >> 6) & 1);
            const int pos = atomicAdd(&cnt[seg], 1);
            if (pos < SCAP) lists[seg * SCAP + pos] = p;
        }
    }
    __syncthreads();

    // ---- Phase 1b: per-seg register gather -> bf16 LDS tile ----
    const int lane = tid & 31;
    const int grp  = tid >> 5;
    for (int seg = grp; seg < 32; seg += 8) {
        const int row = rowbase + (seg >> 1);
        if (row >= n) continue;               // stale tile rows never stored
        const int rel = seg & 1;
        int m = cnt[seg]; if (m > SCAP) m = SCAP;
        const unsigned long long* lst = &lists[seg * SCAP];
        float4 acc = make_float4(0.f, 0.f, 0.f, 0.f);

        int e = 0;
        for (; e + 4 <= m; e += 4) {
            const unsigned long long p0 = lst[e + 0];
            const unsigned long long p1 = lst[e + 1];
            const unsigned long long p2 = lst[e + 2];
            const unsigned long long p3 = lst[e + 3];
            const ushort4 x0 = *(const ushort4*)&Xb[(size_t)(((unsigned)p0 >> 7) & 0xFFFFu) * 128 + lane * 4];
            const ushort4 x1 = *(const ushort4*)&Xb[(size_t)(((unsigned)p1 >> 7) & 0xFFFFu) * 128 + lane * 4];
            const ushort4 x2 = *(const ushort4*)&Xb[(size_t)(((unsigned)p2 >> 7) & 0xFFFFu) * 128 + lane * 4];
            const ushort4 x3 = *(const ushort4*)&Xb[(size_t)(((unsigned)p3 >> 7) & 0xFFFFu) * 128 + lane * 4];
            const float v0 = __uint_as_float((unsigned)(p0 >> 32));
            const float v1 = __uint_as_float((unsigned)(p1 >> 32));
            const float v2 = __uint_as_float((unsigned)(p2 >> 32));
            const float v3 = __uint_as_float((unsigned)(p3 >> 32));
            acc.x = fmaf(v0, b2f(x0.x), acc.x);
            acc.y = fmaf(v0, b2f(x0.y), acc.y);
            acc.z = fmaf(v0, b2f(x0.z), acc.z);
            acc.w = fmaf(v0, b2f(x0.w), acc.w);
            acc.x = fmaf(v1, b2f(x1.x), acc.x);
            acc.y = fmaf(v1, b2f(x1.y), acc.y);
            acc.z = fmaf(v1, b2f(x1.z), acc.z);
            acc.w = fmaf(v1, b2f(x1.w), acc.w);
            acc.x = fmaf(v2, b2f(x2.x), acc.x);
            acc.y = fmaf(v2, b2f(x2.y), acc.y);
            acc.z = fmaf(v2, b2f(x2.z), acc.z);
            acc.w = fmaf(v2, b2f(x2.w), acc.w);
            acc.x = fmaf(v3, b2f(x3.x), acc.x);
            acc.y = fmaf(v3, b2f(x3.y), acc.y);
            acc.z = fmaf(v3, b2f(x3.z), acc.z);
            acc.w = fmaf(v3, b2f(x3.w), acc.w);
        }
        for (; e < m; ++e) {
            const unsigned long long p = lst[e];
            const ushort4 xv = *(const ushort4*)&Xb[(size_t)(((unsigned)p >> 7) & 0xFFFFu) * 128 + lane * 4];
            const float v  = __uint_as_float((unsigned)(p >> 32));
            acc.x = fmaf(v, b2f(xv.x), acc.x);
            acc.y = fmaf(v, b2f(xv.y), acc.y);
            acc.z = fmaf(v, b2f(xv.z), acc.z);
            acc.w = fmaf(v, b2f(xv.w), acc.w);
        }

        ushort4 o;
        o.x = f2bf(acc.x); o.y = f2bf(acc.y); o.z = f2bf(acc.z); o.w = f2bf(acc.w);
        *(ushort4*)&tile[(rel * 16 + (seg >> 1)) * TPITCH + lane * 4] = o;
    }
    __syncthreads();

    // ---- Phase 2: in-block GEMM epilogue on the 16x128 tile ----
    bf16x8 af0[4], af1[4];
    #pragma unroll
    for (int ks = 0; ks < 4; ++ks) {
        af0[ks] = *(const bf16x8*)&tile[(0 * 16 + l15) * TPITCH + ks * 32 + lhi * 8];
        af1[ks] = *(const bf16x8*)&tile[(1 * 16 + l15) * TPITCH + ks * 32 + lhi * 8];
    }

    const f32x4 zero = {0.f, 0.f, 0.f, 0.f};
    f32x4 acc[2];
    acc[0] = zero; acc[1] = zero;
    #pragma unroll
    for (int ks = 0; ks < 4; ++ks) {
        acc[0] = __builtin_amdgcn_mfma_f32_16x16x32_bf16(af0[ks], bfrag[0][0][ks], acc[0], 0, 0, 0);
        acc[1] = __builtin_amdgcn_mfma_f32_16x16x32_bf16(af0[ks], bfrag[0][1][ks], acc[1], 0, 0, 0);
        acc[0] = __builtin_amdgcn_mfma_f32_16x16x32_bf16(af1[ks], bfrag[1][0][ks], acc[0], 0, 0, 0);
        acc[1] = __builtin_amdgcn_mfma_f32_16x16x32_bf16(af1[ks], bfrag[1][1][ks], acc[1], 0, 0, 0);
    }

    #pragma unroll
    for (int ct = 0; ct < 2; ++ct) {
        const int col = colbase + ct * 16 + l15;
        #pragma unroll
        for (int j = 0; j < 4; ++j) {
            const int r = rowbase + lhi * 4 + j;
            if (r < n) out[(size_t)r * 128 + col] = fmaxf(acc[ct][j], 0.f);
        }
    }
}

extern "C" void kernel_launch(void* const* d_in, const int* in_sizes, int n_in,
                              void* d_out, int out_size, void* d_ws, size_t ws_size,
                              hipStream_t stream)
{
    const float* X  = (const float*)d_in[0];
    const int*   r1 = (const int*)  d_in[1];
    const int*   c1 = (const int*)  d_in[2];
    const float* v1 = (const float*)d_in[3];
    const int*   r2 = (const int*)  d_in[4];
    const int*   c2 = (const int*)  d_in[5];
    const float* v2 = (const float*)d_in[6];
    const float* W1 = (const float*)d_in[7];
    const float* W2 = (const float*)d_in[8];
    float*       out = (float*)d_out;

    const int n = in_sizes[0] / 128;   // 50000
    const int E = in_sizes[1];         // 800000

    // Workspace layout (~29 MB):
    //   Xb        : n*128 bf16     (12.8 MB)
    //   Wt        : 2*128*128 bf16 (64 KB)
    //   edges_tmp : NB*BCAP u64    (16.0 MB), 256B-aligned
    //   gcur      : NB ints
    unsigned short* Xb = (unsigned short*)d_ws;
    unsigned short* Wt = Xb + (size_t)n * 128;
    unsigned long long* edges_tmp =
        (unsigned long long*)(((uintptr_t)(Wt + 2 * 128 * 128) + 255) & ~(uintptr_t)255);
    int* gcur = (int*)(edges_tmp + (size_t)NB * BCAP);

    hipMemsetAsync(gcur, 0, NB * sizeof(int), stream);

    // 1) bin + convert (fused, disjoint block ranges)
    convbin_kernel<<<BING + CONVG, 256, 0, stream>>>(
        X, W1, W2, r1, c1, v1, r2, c2, v2, Xb, Wt, gcur, edges_tmp, E, n);

    // 2) aggregate + GEMM + ReLU (fused, one block per 16-row quarter)
    aggemm_kernel<<<NB * 4, 256, 0, stream>>>(gcur, edges_tmp, Xb, Wt, out, n);
}

// Round 13
// 137.429 us; speedup vs baseline: 1.3796x; 1.0023x over previous
//
#include <hip/hip_runtime.h>

// N=50000, E=800000 (per relation), D=128, O=128, fp32 in/out.
// out = relu( spmm(adj1, X@W1) + spmm(adj2, X@W2) )
//      = relu( spmm(adj1, X) @ W1 + spmm(adj2, X) @ W2 )   [associativity]
//
// Pipeline (all on `stream`, graph-capture safe):
//   convbin: [blocks 0..511]  bin: edges -> 782 64-row buckets, LDS
//            write-combined packs {val:f32 | col:16 | rel:1 | rowLocal:6}.
//            [blocks 512..767] convert: Xb = bf16(X), Wt = bf16(W^T).
//   aggemm:  one block per 16-row quarter (grid 3128, m204 swizzle).
//            Phase 1 (r7-proven): scan bucket list, scatter into 32
//            fixed-stride LDS seg-lists, per-seg 32-lane register gather
//            sum(val * Xb[col]) -> bf16 tile in LDS (pitch 136 = 2-way-free).
//            Phase 2: 4 waves MFMA the 16x128 tile against L2-resident Wt
//            (2 rels accumulated), fused ReLU, direct fp32 out store.
//            Deletes: agg global store, agg re-read, separate gemm launch.
//
// r11 lesson (measured): XCD pinning via blockIdx&7 is NOT durable (FETCH
// 150->226MB); never build locality on workgroup->XCD assignment.
// r9 lesson: work-stealing kills locality. Static swizzled chunks only.

typedef __attribute__((ext_vector_type(4))) float     f32x4;
typedef __attribute__((ext_vector_type(8))) short     bf16x8;

#define NB      782     // 64-row buckets: ceil(50000/64)
#define BSLOTS  10      // LDS staging slots per bucket in bin
#define BCAP    2560    // capacity per bucket (mean 2048, ~11 sigma slack)
#define SCAP    64      // per (row,rel) seg capacity (mean 16; P(>64)~2e-18)
#define BING    512     // bin blocks
#define CONVG   256     // convert blocks
#define TPITCH  136     // LDS tile pitch in shorts (17*16B -> bank-friendly)

static __device__ __forceinline__ unsigned short f2bf(float f) {
    unsigned u = __float_as_uint(f);
    u += 0x7FFF + ((u >> 16) & 1);           // round-to-nearest-even
    return (unsigned short)(u >> 16);
}
static __device__ __forceinline__ float b2f(unsigned short s) {
    return __uint_as_float((unsigned)s << 16);
}

// ---------------------------------------------------------------------------
// Fused: bin (blocks < BING) + convert (blocks >= BING).
// ---------------------------------------------------------------------------
__global__ __launch_bounds__(256) void convbin_kernel(
    const float* __restrict__ X,
    const float* __restrict__ W1, const float* __restrict__ W2,
    const int* __restrict__ rows1, const int* __restrict__ cols1, const float* __restrict__ vals1,
    const int* __restrict__ rows2, const int* __restrict__ cols2, const float* __restrict__ vals2,
    unsigned short* __restrict__ Xb, unsigned short* __restrict__ Wt,
    int* __restrict__ gcur, unsigned long long* __restrict__ edges_tmp,
    int E, int n)
{
    if (blockIdx.x >= BING) {
        // ---- convert role ----
        const int stride = CONVG * 256;
        const int nW = 2 * 128 * 128;
        const int nX = n * 32;               // float4 count
        const int total = nW + nX;
        for (int g = (blockIdx.x - BING) * 256 + threadIdx.x; g < total; g += stride) {
            if (g < nW) {
                const int rel = g >> 14;
                const int o   = (g >> 7) & 127;
                const int k   = g & 127;
                const float* W = rel ? W2 : W1;
                Wt[g] = f2bf(W[k * 128 + o]);
            } else {
                const int i = g - nW;
                const float4 v = ((const float4*)X)[i];
                ushort4 b;
                b.x = f2bf(v.x); b.y = f2bf(v.y); b.z = f2bf(v.z); b.w = f2bf(v.w);
                ((ushort4*)Xb)[i] = b;
            }
        }
        return;
    }

    // ---- bin role (r7/r10-proven) ----
    __shared__ unsigned long long stage[NB][BSLOTS];
    __shared__ int scnt[NB];

    for (int i = threadIdx.x; i < NB; i += 256) scnt[i] = 0;
    __syncthreads();

    const int stride = BING * 256;
    const int total  = 2 * E;
    for (int g = blockIdx.x * 256 + threadIdx.x; g < total; g += stride) {
        int r, col, rel; float v;
        if (g < E) { r = rows1[g]; col = cols1[g]; rel = 0; v = vals1[g]; }
        else       { int e = g - E; r = rows2[e]; col = cols2[e]; rel = 1; v = vals2[e]; }

        const int b = r >> 6;
        const unsigned lo = (unsigned)(r & 63) | ((unsigned)rel << 6) | ((unsigned)col << 7);
        const unsigned long long pack =
            (unsigned long long)lo | ((unsigned long long)__float_as_uint(v) << 32);

        const int pos = atomicAdd(&scnt[b], 1);
        if (pos < BSLOTS) {
            stage[b][pos] = pack;
        } else {                                  // overflow: direct write
            int gp = atomicAdd(&gcur[b], 1);
            if (gp < BCAP) edges_tmp[(size_t)b * BCAP + gp] = pack;
        }
    }
    __syncthreads();

    for (int b = threadIdx.x; b < NB; b += 256) {
        int k = scnt[b]; if (k > BSLOTS) k = BSLOTS;
        if (k > 0) {
            int base = atomicAdd(&gcur[b], k);
            for (int i = 0; i < k; ++i)
                if (base + i < BCAP)
                    edges_tmp[(size_t)b * BCAP + base + i] = stage[b][i];
        }
    }
}

// ---------------------------------------------------------------------------
// Aggemm: block = 16-row quarter-bucket. Gather into LDS bf16 tile, then
// in-block MFMA epilogue (out = relu(tile0 @ W1 + tile1 @ W2)).
// A-frag: row = lane&15, k = (lane>>4)*8 + j. C/D: col=lane&15,
// row=(lane>>4)*4+reg  [m89-verified].
// ---------------------------------------------------------------------------
__global__ __launch_bounds__(256) void aggemm_kernel(
    const int* __restrict__ gcur,
    const unsigned long long* __restrict__ edges_tmp,
    const unsigned short* __restrict__ Xb,
    const unsigned short* __restrict__ Wt,
    float* __restrict__ out, int n)
{
    __shared__ unsigned long long lists[32 * SCAP];       // 16 KB
    __shared__ int cnt[32];
    __shared__ unsigned short tile[2 * 16 * TPITCH];      // 8.5 KB, pitch 136

    const int tid = threadIdx.x;
    const int NQ  = NB * 4;                  // 3128 = 8 * 391
    // m204 bijective XCD swizzle (r8=0): consecutive swz (same bucket's
    // quarters) dispatch adjacently -> bucket edge-list reads L2-friendly.
    const int xcd = blockIdx.x & 7, bi = blockIdx.x >> 3;
    const int swz = xcd * (NQ >> 3) + bi;

    const int b   = swz >> 2;
    const int q   = swz & 3;
    const int rowbase = swz * 16;
    if (rowbase >= n) return;

    // ---- load B fragments early (hides under gather) ----
    const int lane64 = tid & 63;
    const int w      = tid >> 6;
    const int colbase = w * 32;
    const int l15 = lane64 & 15;
    const int lhi = lane64 >> 4;

    bf16x8 bfrag[2][2][4];                   // [rel][ct][ks]
    #pragma unroll
    for (int rel = 0; rel < 2; ++rel) {
        const unsigned short* Wr = Wt + rel * 16384;
        #pragma unroll
        for (int ct = 0; ct < 2; ++ct) {
            const int o = colbase + ct * 16 + l15;
            #pragma unroll
            for (int ks = 0; ks < 4; ++ks)
                bfrag[rel][ct][ks] = *(const bf16x8*)&Wr[o * 128 + ks * 32 + lhi * 8];
        }
    }

    int sz = gcur[b]; if (sz > BCAP) sz = BCAP;
    const unsigned long long* ebase = edges_tmp + (size_t)b * BCAP;

    if (tid < 32) cnt[tid] = 0;
    __syncthreads();

    // ---- Phase 1a: filter quarter, append to per-seg LDS lists ----
    for (int e = tid; e < sz; e += 256) {
        const unsigned long long p = ebase[e];
        const unsigned lo = (unsigned)p;
        const int rl = (int)(lo & 63u);
        if ((rl >> 4) == q) {
            const int seg = ((rl & 15) << 1) | ((lo >> 6) & 1);
            const int pos = atomicAdd(&cnt[seg], 1);
            if (pos < SCAP) lists[seg * SCAP + pos] = p;
        }
    }
    __syncthreads();

    // ---- Phase 1b: per-seg register gather -> bf16 LDS tile ----
    const int lane = tid & 31;
    const int grp  = tid >> 5;
    for (int seg = grp; seg < 32; seg += 8) {
        const int row = rowbase + (seg >> 1);
        if (row >= n) continue;               // stale tile rows never stored
        const int rel = seg & 1;
        int m = cnt[seg]; if (m > SCAP) m = SCAP;
        const unsigned long long* lst = &lists[seg * SCAP];
        float4 acc = make_float4(0.f, 0.f, 0.f, 0.f);

        int e = 0;
        for (; e + 4 <= m; e += 4) {
            const unsigned long long p0 = lst[e + 0];
            const unsigned long long p1 = lst[e + 1];
            const unsigned long long p2 = lst[e + 2];
            const unsigned long long p3 = lst[e + 3];
            const ushort4 x0 = *(const ushort4*)&Xb[(size_t)(((unsigned)p0 >> 7) & 0xFFFFu) * 128 + lane * 4];
            const ushort4 x1 = *(const ushort4*)&Xb[(size_t)(((unsigned)p1 >> 7) & 0xFFFFu) * 128 + lane * 4];
            const ushort4 x2 = *(const ushort4*)&Xb[(size_t)(((unsigned)p2 >> 7) & 0xFFFFu) * 128 + lane * 4];
            const ushort4 x3 = *(const ushort4*)&Xb[(size_t)(((unsigned)p3 >> 7) & 0xFFFFu) * 128 + lane * 4];
            const float v0 = __uint_as_float((unsigned)(p0 >> 32));
            const float v1 = __uint_as_float((unsigned)(p1 >> 32));
            const float v2 = __uint_as_float((unsigned)(p2 >> 32));
            const float v3 = __uint_as_float((unsigned)(p3 >> 32));
            acc.x = fmaf(v0, b2f(x0.x), acc.x);
            acc.y = fmaf(v0, b2f(x0.y), acc.y);
            acc.z = fmaf(v0, b2f(x0.z), acc.z);
            acc.w = fmaf(v0, b2f(x0.w), acc.w);
            acc.x = fmaf(v1, b2f(x1.x), acc.x);
            acc.y = fmaf(v1, b2f(x1.y), acc.y);
            acc.z = fmaf(v1, b2f(x1.z), acc.z);
            acc.w = fmaf(v1, b2f(x1.w), acc.w);
            acc.x = fmaf(v2, b2f(x2.x), acc.x);
            acc.y = fmaf(v2, b2f(x2.y), acc.y);
            acc.z = fmaf(v2, b2f(x2.z), acc.z);
            acc.w = fmaf(v2, b2f(x2.w), acc.w);
            acc.x = fmaf(v3, b2f(x3.x), acc.x);
            acc.y = fmaf(v3, b2f(x3.y), acc.y);
            acc.z = fmaf(v3, b2f(x3.z), acc.z);
            acc.w = fmaf(v3, b2f(x3.w), acc.w);
        }
        for (; e < m; ++e) {
            const unsigned long long p = lst[e];
            const ushort4 xv = *(const ushort4*)&Xb[(size_t)(((unsigned)p >> 7) & 0xFFFFu) * 128 + lane * 4];
            const float v  = __uint_as_float((unsigned)(p >> 32));
            acc.x = fmaf(v, b2f(xv.x), acc.x);
            acc.y = fmaf(v, b2f(xv.y), acc.y);
            acc.z = fmaf(v, b2f(xv.z), acc.z);
            acc.w = fmaf(v, b2f(xv.w), acc.w);
        }

        ushort4 o;
        o.x = f2bf(acc.x); o.y = f2bf(acc.y); o.z = f2bf(acc.z); o.w = f2bf(acc.w);
        *(ushort4*)&tile[(rel * 16 + (seg >> 1)) * TPITCH + lane * 4] = o;
    }
    __syncthreads();

    // ---- Phase 2: in-block GEMM epilogue on the 16x128 tile ----
    bf16x8 af0[4], af1[4];
    #pragma unroll
    for (int ks = 0; ks < 4; ++ks) {
        af0[ks] = *(const bf16x8*)&tile[(0 * 16 + l15) * TPITCH + ks * 32 + lhi * 8];
        af1[ks] = *(const bf16x8*)&tile[(1 * 16 + l15) * TPITCH + ks * 32 + lhi * 8];
    }

    const f32x4 zero = {0.f, 0.f, 0.f, 0.f};
    f32x4 acc[2];
    acc[0] = zero; acc[1] = zero;
    #pragma unroll
    for (int ks = 0; ks < 4; ++ks) {
        acc[0] = __builtin_amdgcn_mfma_f32_16x16x32_bf16(af0[ks], bfrag[0][0][ks], acc[0], 0, 0, 0);
        acc[1] = __builtin_amdgcn_mfma_f32_16x16x32_bf16(af0[ks], bfrag[0][1][ks], acc[1], 0, 0, 0);
        acc[0] = __builtin_amdgcn_mfma_f32_16x16x32_bf16(af1[ks], bfrag[1][0][ks], acc[0], 0, 0, 0);
        acc[1] = __builtin_amdgcn_mfma_f32_16x16x32_bf16(af1[ks], bfrag[1][1][ks], acc[1], 0, 0, 0);
    }

    #pragma unroll
    for (int ct = 0; ct < 2; ++ct) {
        const int col = colbase + ct * 16 + l15;
        #pragma unroll
        for (int j = 0; j < 4; ++j) {
            const int r = rowbase + lhi * 4 + j;
            if (r < n) out[(size_t)r * 128 + col] = fmaxf(acc[ct][j], 0.f);
        }
    }
}

extern "C" void kernel_launch(void* const* d_in, const int* in_sizes, int n_in,
                              void* d_out, int out_size, void* d_ws, size_t ws_size,
                              hipStream_t stream)
{
    const float* X  = (const float*)d_in[0];
    const int*   r1 = (const int*)  d_in[1];
    const int*   c1 = (const int*)  d_in[2];
    const float* v1 = (const float*)d_in[3];
    const int*   r2 = (const int*)  d_in[4];
    const int*   c2 = (const int*)  d_in[5];
    const float* v2 = (const float*)d_in[6];
    const float* W1 = (const float*)d_in[7];
    const float* W2 = (const float*)d_in[8];
    float*       out = (float*)d_out;

    const int n = in_sizes[0] / 128;   // 50000
    const int E = in_sizes[1];         // 800000

    // Workspace layout (~29 MB):
    //   Xb        : n*128 bf16     (12.8 MB)
    //   Wt        : 2*128*128 bf16 (64 KB)
    //   edges_tmp : NB*BCAP u64    (16.0 MB), 256B-aligned
    //   gcur      : NB ints
    unsigned short* Xb = (unsigned short*)d_ws;
    unsigned short* Wt = Xb + (size_t)n * 128;
    unsigned long long* edges_tmp =
        (unsigned long long*)(((uintptr_t)(Wt + 2 * 128 * 128) + 255) & ~(uintptr_t)255);
    int* gcur = (int*)(edges_tmp + (size_t)NB * BCAP);

    hipMemsetAsync(gcur, 0, NB * sizeof(int), stream);

    // 1) bin + convert (fused, disjoint block ranges)
    convbin_kernel<<<BING + CONVG, 256, 0, stream>>>(
        X, W1, W2, r1, c1, v1, r2, c2, v2, Xb, Wt, gcur, edges_tmp, E, n);

    // 2) aggregate + GEMM + ReLU (fused, one block per 16-row quarter)
    aggemm_kernel<<<NB * 4, 256, 0, stream>>>(gcur, edges_tmp, Xb, Wt, out, n);
}